// Round 7
// baseline (77.125 us; speedup 1.0000x reference)
//
#include <hip/hip_runtime.h>
#include <hip/hip_bf16.h>
#include <math.h>

// ProbaV cPSNR:  loss(u,v) = E[d^2] - (E[d])^2,  d = ct - pm_window(u,v)
// S1(u,v) = T1 - W1(u,v);  S2(u,v) = T2 - 2*CC(u,v) + W2(u,v)
//   T1,T2   : sum ct, sum ct^2            (ct = target*mask, inner 378x378 @ +3)
//   CC(u,v) : sum ct[r][c] * pm[r+u][c+v] (pm = predict*mask)
//   W1,W2   : window sums of pm, pm^2 over rows [u,u+378) x cols [v,v+378)
// W = Total - BR(u) - BC(v) + X(u,v)  (inclusion-exclusion, rows 0..382 x cols 0..383)
//
// R7 structure: 64-thread (1-wave) blocks, 3-row x 8-col per thread (lowest
// mem-instr tiling, 13.5M quads), in-wave shfl_xor butterfly reduction (no LDS),
// XCD-chunked block swizzle for L2 locality, two plain dispatches
// (single-dispatch threadfence ticket = 200us fence storm, R5).

#define NIMG 32
#define IMGSZ (384 * 384)
#define NRT 126                  // row tiles (3 ct rows each)
#define NSG 48                   // col segments (8 cols)
#define NCC 3024                 // cc blocks = 32*126*48/64
#define NEDGEB 32                // 1 edge block per image
#define NTOT (NCC + NEDGEB)      // 3056 = 8 * 382
#define CHUNK 382                // blocks per XCD chunk
#define NM 40                    // cc[36], t1, t2, tot1, tot2
#define MSTRIDE 3024             // mpart col-major [NM][MSTRIDE]
#define MQUADS 756               // MSTRIDE/4
#define NE 262                   // edge entries per image

__global__ __launch_bounds__(64, 2) void probav_fused_kernel(
    const float* __restrict__ predict,
    const float* __restrict__ target,
    const float* __restrict__ mask,
    float* __restrict__ mpart /* [NM][MSTRIDE] */,
    double* __restrict__ epart /* [NE][NIMG] */) {

  // XCD-chunked swizzle: hardware round-robins blockIdx across 8 XCDs;
  // remap so each XCD owns a contiguous logical range (bijective, 3056=8*382).
  const int lbid = (blockIdx.x & 7) * CHUNK + (blockIdx.x >> 3);
  const int t = threadIdx.x;     // 0..63 (one wave)

  if (lbid >= NEDGEB) {
    // ---------------- cc path: 3 ct rows x 8 cols per thread ----------------
    const int cb  = lbid - NEDGEB;
    const int tid = cb * 64 + t;
    const int img = tid / (NRT * NSG);
    const int rem = tid - img * (NRT * NSG);
    const int rt  = rem / NSG;
    const int sg  = rem - rt * NSG;
    const int r0  = rt * 3;
    const int jb  = sg * 8;
    const size_t base = (size_t)img * IMGSZ;

    // ct tile: rows r0+3..r0+5 (input), cols jb+3..jb+10 via 3 aligned quads
    float ct[3][8];
    float t1 = 0.f, t2 = 0.f;
#pragma unroll
    for (int rr = 0; rr < 3; ++rr) {
      const float4* tq = reinterpret_cast<const float4*>(target + base + (size_t)(r0 + rr + 3) * 384 + jb);
      const float4* mq = reinterpret_cast<const float4*>(mask   + base + (size_t)(r0 + rr + 3) * 384 + jb);
      float tv[12], mv[12];
#pragma unroll
      for (int q = 0; q < 3; ++q) {
        float4 a = tq[q];
        float4 b = mq[q];
        tv[4 * q + 0] = a.x; tv[4 * q + 1] = a.y; tv[4 * q + 2] = a.z; tv[4 * q + 3] = a.w;
        mv[4 * q + 0] = b.x; mv[4 * q + 1] = b.y; mv[4 * q + 2] = b.z; mv[4 * q + 3] = b.w;
      }
#pragma unroll
      for (int x = 0; x < 8; ++x) {
        float v = tv[3 + x] * mv[3 + x];
        v = (jb + x < 378) ? v : 0.f;
        ct[rr][x] = v;
        t1 += v;
        t2 = fmaf(v, v, t2);
      }
    }

    float cc[36];
#pragma unroll
    for (int o = 0; o < 36; ++o) cc[o] = 0.f;
    float tot1 = 0.f, tot2 = 0.f;
    const int ownR = (rt == NRT - 1) ? 8 : 3;   // rt=125 owns pm rows 375..382

#pragma unroll
    for (int R = 0; R < 8; ++R) {
      const float4* pq = reinterpret_cast<const float4*>(predict + base + (size_t)(r0 + R) * 384 + jb);
      const float4* mq = reinterpret_cast<const float4*>(mask    + base + (size_t)(r0 + R) * 384 + jb);
      float pm[16];
#pragma unroll
      for (int q = 0; q < 4; ++q) {
        float4 a = pq[q];
        float4 b = mq[q];
        pm[4 * q + 0] = a.x * b.x;
        pm[4 * q + 1] = a.y * b.y;
        pm[4 * q + 2] = a.z * b.z;
        pm[4 * q + 3] = a.w * b.w;
      }
      if (R < ownR) {
#pragma unroll
        for (int x = 0; x < 8; ++x) {
          tot1 += pm[x];
          tot2 = fmaf(pm[x], pm[x], tot2);
        }
      }
      const int rlo = (R > 5) ? (R - 5) : 0;
      const int rhi = (R < 2) ? R : 2;
#pragma unroll
      for (int rr = rlo; rr <= rhi; ++rr) {
        const int u = R - rr;
#pragma unroll
        for (int v = 0; v < 6; ++v) {
#pragma unroll
          for (int x = 0; x < 8; ++x) {
            cc[u * 6 + v] = fmaf(ct[rr][x], pm[v + x], cc[u * 6 + v]);
          }
        }
      }
    }

    // in-wave butterfly reduction; lane o keeps value o; one coalesced store
    float outv = 0.f;
#pragma unroll
    for (int o = 0; o < 36; ++o) {
      float a = cc[o];
#pragma unroll
      for (int off = 32; off > 0; off >>= 1) a += __shfl_xor(a, off);
      if (t == o) outv = a;
    }
    {
      float a = t1, b = t2, c = tot1, d = tot2;
#pragma unroll
      for (int off = 32; off > 0; off >>= 1) {
        a += __shfl_xor(a, off);
        b += __shfl_xor(b, off);
        c += __shfl_xor(c, off);
        d += __shfl_xor(d, off);
      }
      if (t == 36) outv = a;
      if (t == 37) outv = b;
      if (t == 38) outv = c;
      if (t == 39) outv = d;
    }
    if (t < NM) mpart[t * MSTRIDE + cb] = outv;

  } else {
    // ---------------- edge path: one 64-thread block per image ----------------
    const int img = lbid;
    const size_t base = (size_t)img * IMGSZ;

    // Phase A: full-row sums, rows {0..4, 378..382}, cols 0..383
#pragma unroll
    for (int ridx = 0; ridx < 10; ++ridx) {
      const int row = (ridx < 5) ? ridx : (373 + ridx);
      const float* pr = predict + base + (size_t)row * 384;
      const float* mr = mask    + base + (size_t)row * 384;
      double e1 = 0.0, e2 = 0.0;
      for (int c = t; c < 384; c += 64) {
        float v = pr[c] * mr[c];
        e1 += v;
        e2 += (double)v * v;
      }
#pragma unroll
      for (int off = 32; off > 0; off >>= 1) {
        e1 += __shfl_xor(e1, off);
        e2 += __shfl_xor(e2, off);
      }
      if (t == 0) {
        epart[(size_t)(ridx)      * NIMG + img] = e1;
        epart[(size_t)(10 + ridx) * NIMG + img] = e2;
      }
    }

    // Phase B: full-col sums, cols {0..4, 378..383}, rows 0..382
#pragma unroll
    for (int cidx = 0; cidx < 11; ++cidx) {
      const int col = (cidx < 5) ? cidx : (373 + cidx);
      double f1 = 0.0, f2 = 0.0;
      for (int r = t; r < 383; r += 64) {
        float v = predict[base + (size_t)r * 384 + col] * mask[base + (size_t)r * 384 + col];
        f1 += v;
        f2 += (double)v * v;
      }
#pragma unroll
      for (int off = 32; off > 0; off >>= 1) {
        f1 += __shfl_xor(f1, off);
        f2 += __shfl_xor(f2, off);
      }
      if (t == 0) {
        epart[(size_t)(20 + cidx) * NIMG + img] = f1;
        epart[(size_t)(31 + cidx) * NIMG + img] = f2;
      }
    }

    // Phase C: corner table 10x11
    for (int k = t; k < 110; k += 64) {
      const int ridx = k / 11, cidx = k % 11;
      const int row = (ridx < 5) ? ridx : (373 + ridx);
      const int col = (cidx < 5) ? cidx : (373 + cidx);
      float v = predict[base + (size_t)row * 384 + col] * mask[base + (size_t)row * 384 + col];
      epart[(size_t)(42 + k)  * NIMG + img] = (double)v;
      epart[(size_t)(152 + k) * NIMG + img] = (double)v * v;
    }
  }
}

// ---------------- final kernel: assemble 36 losses, min, score ----------------
__global__ void probav_final_kernel(const float* __restrict__ mpart,
                                    const double* __restrict__ epart,
                                    float* __restrict__ out) {
  __shared__ double M[NM];
  __shared__ double E[NE];
  __shared__ double Etmp[524];
  __shared__ double loss[36];
  const int t = threadIdx.x;          // 1024 threads
  const int lane = t & 63;
  const int w = t >> 6;               // 16 waves

  // M: 40 columns; each column is MSTRIDE contiguous floats = MQUADS float4s
  for (int v = w; v < NM; v += 16) {
    const float4* qp = reinterpret_cast<const float4*>(mpart + v * MSTRIDE);
    double s = 0.0;
    for (int i = lane; i < MQUADS; i += 64) {
      float4 q = qp[i];
      s += (double)q.x + (double)q.y + (double)q.z + (double)q.w;
    }
#pragma unroll
    for (int off = 32; off > 0; off >>= 1) s += __shfl_down(s, off);
    if (lane == 0) M[v] = s;
  }
  // E: 262 entries x 32 contiguous doubles, 2 threads per entry
  if (t < 524) {
    const int e = t >> 1, si = t & 1;
    double s = 0.0;
    for (int i = si * 16; i < si * 16 + 16; ++i) s += epart[(size_t)e * NIMG + i];
    Etmp[t] = s;
  }
  __syncthreads();
  if (t < NE) E[t] = Etmp[2 * t] + Etmp[2 * t + 1];
  __syncthreads();

  if (t < 36) {
    const int u = t / 6, v = t % 6;
    double br1 = 0, br2 = 0, bc1 = 0, bc2 = 0, x1 = 0, x2 = 0;
    int rset[5], nr = 0;
    for (int j = 0; j < u; ++j) rset[nr++] = j;
    for (int j = 5 + u; j < 10; ++j) rset[nr++] = j;
    int cset[6], nc = 0;
    for (int j = 0; j < v; ++j) cset[nc++] = j;
    for (int j = 5 + v; j < 11; ++j) cset[nc++] = j;
    for (int a = 0; a < nr; ++a) { br1 += E[rset[a]]; br2 += E[10 + rset[a]]; }
    for (int b = 0; b < nc; ++b) { bc1 += E[20 + cset[b]]; bc2 += E[31 + cset[b]]; }
    for (int a = 0; a < nr; ++a)
      for (int b = 0; b < nc; ++b) {
        x1 += E[42 + rset[a] * 11 + cset[b]];
        x2 += E[152 + rset[a] * 11 + cset[b]];
      }
    const double T1 = M[36], T2 = M[37];
    const double W1 = M[38] - br1 - bc1 + x1;
    const double W2 = M[39] - br2 - bc2 + x2;
    const double CCv = M[t];
    const double N = 32.0 * 378.0 * 378.0;
    const double S1 = T1 - W1;
    const double S2 = T2 - 2.0 * CCv + W2;
    loss[t] = S2 / N - (S1 / N) * (S1 / N);
  }
  __syncthreads();
  if (t == 0) {
    double best = loss[0];
    for (int o = 1; o < 36; ++o) best = fmin(best, loss[o]);
    out[0] = (float)(-10.0 * log10(best));
  }
}

extern "C" void kernel_launch(void* const* d_in, const int* in_sizes, int n_in,
                              void* d_out, int out_size, void* d_ws, size_t ws_size,
                              hipStream_t stream) {
  const float* predict = (const float*)d_in[0];
  const float* target  = (const float*)d_in[1];
  const float* mask    = (const float*)d_in[2];
  float* out = (float*)d_out;

  float*  mpart = (float*)d_ws;                               // 40*3024*4 = 483840 B
  double* epart = (double*)((char*)d_ws + NM * MSTRIDE * 4);  // 262*32*8  =  67072 B

  probav_fused_kernel<<<NTOT, 64, 0, stream>>>(predict, target, mask, mpart, epart);
  probav_final_kernel<<<1, 1024, 0, stream>>>(mpart, epart, out);
}

// Round 8
// 50.694 us; speedup vs baseline: 1.5214x; 1.5214x over previous
//
#include <hip/hip_runtime.h>
#include <hip/hip_bf16.h>
#include <math.h>

// ProbaV cPSNR:  loss(u,v) = E[d^2] - (E[d])^2,  d = ct - pm_window(u,v)
// S1(u,v) = T1 - W1(u,v);  S2(u,v) = T2 - 2*CC(u,v) + W2(u,v)
//   T1,T2   : sum ct, sum ct^2            (ct = target*mask, inner 378x378 @ +3)
//   CC(u,v) : sum ct[r][c] * pm[r+u][c+v] (pm = predict*mask)
//   W1,W2   : window sums of pm, pm^2 over rows [u,u+378) x cols [v,v+378)
// W = Total - BR(u) - BC(v) + X(u,v)  (inclusion-exclusion, rows 0..382 x cols 0..383)
//
// R8: R3's 3-row x 8-col thread tiling (lowest mem-instr count) +
// __launch_bounds__(256) with NO waves-per-eu arg (R3/R6/R7 post-mortems:
// the 2nd arg empirically CAPS residency at that many blocks/CU on this
// stack) + XCD-chunked bijective swizzle (R7: FETCH 48->32.5 MB).
// Two plain dispatches (single-dispatch fence ticket = 200us storm, R5).

#define NIMG 32
#define IMGSZ (384 * 384)
#define NRT 126                  // row tiles (3 ct rows each)
#define NSG 48                   // col segments (8 cols)
#define NCC 756                  // cc blocks = 32*126*48/256
#define NEDGE 64                 // 2 per image
#define NTOT (NCC + NEDGE)       // 820 logical blocks
#define NPAD 824                 // padded grid: 8 * 103 (bijective swizzle)
#define CHUNK 103
#define NM 40                    // cc[36], t1, t2, tot1, tot2
#define MSTRIDE 756              // mpart col-major [NM][MSTRIDE]
#define MQUADS 189               // MSTRIDE/4
#define NE 262                   // edge entries per image

__global__ __launch_bounds__(256) void probav_fused_kernel(
    const float* __restrict__ predict,
    const float* __restrict__ target,
    const float* __restrict__ mask,
    float* __restrict__ mpart /* [NM][MSTRIDE] */,
    double* __restrict__ epart /* [NE][NIMG] */) {

  // XCD-chunked swizzle: bijective 0..823 -> 0..823 (824 = 8*103); pad blocks exit.
  const int lbid = (blockIdx.x & 7) * CHUNK + (blockIdx.x >> 3);
  if (lbid >= NTOT) return;

  __shared__ double shbuf[506];
  const int t = threadIdx.x;
  const int lane = t & 63;
  const int w = t >> 6;

  if (lbid >= NEDGE) {
    // ---------------- cc path: 3 ct rows x 8 cols per thread ----------------
    const int cb  = lbid - NEDGE;
    const int tid = cb * 256 + t;
    const int img = tid / (NRT * NSG);
    const int rem = tid - img * (NRT * NSG);
    const int rt  = rem / NSG;
    const int sg  = rem - rt * NSG;
    const int r0  = rt * 3;
    const int jb  = sg * 8;
    const size_t base = (size_t)img * IMGSZ;

    // ct tile: input rows r0+3..r0+5, cols jb+3..jb+10 via 3 aligned quads
    float ct[3][8];
    float t1 = 0.f, t2 = 0.f;
#pragma unroll
    for (int rr = 0; rr < 3; ++rr) {
      const float4* tq = reinterpret_cast<const float4*>(target + base + (size_t)(r0 + rr + 3) * 384 + jb);
      const float4* mq = reinterpret_cast<const float4*>(mask   + base + (size_t)(r0 + rr + 3) * 384 + jb);
      float tv[12], mv[12];
#pragma unroll
      for (int q = 0; q < 3; ++q) {
        float4 a = tq[q];
        float4 b = mq[q];
        tv[4 * q + 0] = a.x; tv[4 * q + 1] = a.y; tv[4 * q + 2] = a.z; tv[4 * q + 3] = a.w;
        mv[4 * q + 0] = b.x; mv[4 * q + 1] = b.y; mv[4 * q + 2] = b.z; mv[4 * q + 3] = b.w;
      }
#pragma unroll
      for (int x = 0; x < 8; ++x) {
        float v = tv[3 + x] * mv[3 + x];
        v = (jb + x < 378) ? v : 0.f;
        ct[rr][x] = v;
        t1 += v;
        t2 = fmaf(v, v, t2);
      }
    }

    float cc[36];
#pragma unroll
    for (int o = 0; o < 36; ++o) cc[o] = 0.f;
    float tot1 = 0.f, tot2 = 0.f;
    const int ownR = (rt == NRT - 1) ? 8 : 3;   // rt=125 owns pm rows 375..382

#pragma unroll
    for (int R = 0; R < 8; ++R) {
      const float4* pq = reinterpret_cast<const float4*>(predict + base + (size_t)(r0 + R) * 384 + jb);
      const float4* mq = reinterpret_cast<const float4*>(mask    + base + (size_t)(r0 + R) * 384 + jb);
      float pm[16];
#pragma unroll
      for (int q = 0; q < 4; ++q) {
        float4 a = pq[q];
        float4 b = mq[q];
        pm[4 * q + 0] = a.x * b.x;
        pm[4 * q + 1] = a.y * b.y;
        pm[4 * q + 2] = a.z * b.z;
        pm[4 * q + 3] = a.w * b.w;
      }
      if (R < ownR) {
#pragma unroll
        for (int x = 0; x < 8; ++x) {
          tot1 += pm[x];
          tot2 = fmaf(pm[x], pm[x], tot2);
        }
      }
      const int rlo = (R > 5) ? (R - 5) : 0;
      const int rhi = (R < 2) ? R : 2;
#pragma unroll
      for (int rr = rlo; rr <= rhi; ++rr) {
        const int u = R - rr;
#pragma unroll
        for (int v = 0; v < 6; ++v) {
#pragma unroll
          for (int x = 0; x < 8; ++x) {
            cc[u * 6 + v] = fmaf(ct[rr][x], pm[v + x], cc[u * 6 + v]);
          }
        }
      }
    }

    // block reduction: 40 floats -> mpart column-major
    float* red = reinterpret_cast<float*>(shbuf);  // [4][NM]
#pragma unroll
    for (int o = 0; o < 36; ++o) {
      float a = cc[o];
#pragma unroll
      for (int off = 32; off > 0; off >>= 1) a += __shfl_down(a, off);
      if (lane == 0) red[w * NM + o] = a;
    }
    {
      float a = t1, b = t2, c = tot1, d = tot2;
#pragma unroll
      for (int off = 32; off > 0; off >>= 1) {
        a += __shfl_down(a, off);
        b += __shfl_down(b, off);
        c += __shfl_down(c, off);
        d += __shfl_down(d, off);
      }
      if (lane == 0) { red[w * NM + 36] = a; red[w * NM + 37] = b; red[w * NM + 38] = c; red[w * NM + 39] = d; }
    }
    __syncthreads();
    if (t < NM) {
      float v = red[0 * NM + t] + red[1 * NM + t] + red[2 * NM + t] + red[3 * NM + t];
      mpart[t * MSTRIDE + cb] = v;
    }
  } else {
    // ---------------- edge path: 2 blocks per image ----------------
    const int img = lbid >> 1;
    const int slice = lbid & 1;
    const size_t base = (size_t)img * IMGSZ;
    double* sh = shbuf;

    if (slice == 0) {
      // full-row sums, rows {0..4, 378..382}, cols 0..383
      if (t < 250) {
        const int ridx = t / 25, cs = t % 25;
        const int row = (ridx < 5) ? ridx : (373 + ridx);
        const float* pr = predict + base + (size_t)row * 384;
        const float* mr = mask    + base + (size_t)row * 384;
        double e1 = 0.0, e2 = 0.0;
        for (int c = cs; c < 384; c += 25) {
          float v = pr[c] * mr[c];
          e1 += v;
          e2 += (double)v * v;
        }
        sh[ridx * 25 + cs] = e1;
        sh[250 + ridx * 25 + cs] = e2;
      }
      __syncthreads();
      if (t < 20) {
        const int kind = t / 10, ridx = t % 10;
        double s = 0.0;
        for (int k = 0; k < 25; ++k) s += sh[kind * 250 + ridx * 25 + k];
        epart[(size_t)(kind * 10 + ridx) * NIMG + img] = s;
      }
      // corner table 10x11
      if (t < 110) {
        const int ridx = t / 11, cidx = t % 11;
        const int row = (ridx < 5) ? ridx : (373 + ridx);
        const int col = (cidx < 5) ? cidx : (373 + cidx);
        float v = predict[base + (size_t)row * 384 + col] * mask[base + (size_t)row * 384 + col];
        epart[(size_t)(42 + t)  * NIMG + img] = (double)v;
        epart[(size_t)(152 + t) * NIMG + img] = (double)v * v;
      }
    } else {
      // full-col sums, cols {0..4, 378..383}, rows 0..382
      if (t < 253) {
        const int cidx = t / 23, rs = t % 23;
        const int col = (cidx < 5) ? cidx : (373 + cidx);
        double f1 = 0.0, f2 = 0.0;
        for (int r = rs; r < 383; r += 23) {
          float v = predict[base + (size_t)r * 384 + col] * mask[base + (size_t)r * 384 + col];
          f1 += v;
          f2 += (double)v * v;
        }
        sh[cidx * 23 + rs] = f1;
        sh[253 + cidx * 23 + rs] = f2;
      }
      __syncthreads();
      if (t < 22) {
        const int kind = t / 11, cidx = t % 11;
        double s = 0.0;
        for (int k = 0; k < 23; ++k) s += sh[kind * 253 + cidx * 23 + k];
        epart[(size_t)(20 + kind * 11 + cidx) * NIMG + img] = s;
      }
    }
  }
}

// ---------------- final kernel: assemble 36 losses, min, score ----------------
__global__ void probav_final_kernel(const float* __restrict__ mpart,
                                    const double* __restrict__ epart,
                                    float* __restrict__ out) {
  __shared__ double M[NM];
  __shared__ double E[NE];
  __shared__ double Etmp[524];
  __shared__ double loss[36];
  const int t = threadIdx.x;          // 1024 threads
  const int lane = t & 63;
  const int w = t >> 6;               // 16 waves

  // M: 40 columns; each column is MSTRIDE contiguous floats = MQUADS float4s
  for (int v = w; v < NM; v += 16) {
    const float4* qp = reinterpret_cast<const float4*>(mpart + v * MSTRIDE);
    double s = 0.0;
    for (int i = lane; i < MQUADS; i += 64) {
      float4 q = qp[i];
      s += (double)q.x + (double)q.y + (double)q.z + (double)q.w;
    }
#pragma unroll
    for (int off = 32; off > 0; off >>= 1) s += __shfl_down(s, off);
    if (lane == 0) M[v] = s;
  }
  // E: 262 entries x 32 contiguous doubles, 2 threads per entry
  if (t < 524) {
    const int e = t >> 1, si = t & 1;
    double s = 0.0;
    for (int i = si * 16; i < si * 16 + 16; ++i) s += epart[(size_t)e * NIMG + i];
    Etmp[t] = s;
  }
  __syncthreads();
  if (t < NE) E[t] = Etmp[2 * t] + Etmp[2 * t + 1];
  __syncthreads();

  if (t < 36) {
    const int u = t / 6, v = t % 6;
    double br1 = 0, br2 = 0, bc1 = 0, bc2 = 0, x1 = 0, x2 = 0;
    int rset[5], nr = 0;
    for (int j = 0; j < u; ++j) rset[nr++] = j;
    for (int j = 5 + u; j < 10; ++j) rset[nr++] = j;
    int cset[6], nc = 0;
    for (int j = 0; j < v; ++j) cset[nc++] = j;
    for (int j = 5 + v; j < 11; ++j) cset[nc++] = j;
    for (int a = 0; a < nr; ++a) { br1 += E[rset[a]]; br2 += E[10 + rset[a]]; }
    for (int b = 0; b < nc; ++b) { bc1 += E[20 + cset[b]]; bc2 += E[31 + cset[b]]; }
    for (int a = 0; a < nr; ++a)
      for (int b = 0; b < nc; ++b) {
        x1 += E[42 + rset[a] * 11 + cset[b]];
        x2 += E[152 + rset[a] * 11 + cset[b]];
      }
    const double T1 = M[36], T2 = M[37];
    const double W1 = M[38] - br1 - bc1 + x1;
    const double W2 = M[39] - br2 - bc2 + x2;
    const double CCv = M[t];
    const double N = 32.0 * 378.0 * 378.0;
    const double S1 = T1 - W1;
    const double S2 = T2 - 2.0 * CCv + W2;
    loss[t] = S2 / N - (S1 / N) * (S1 / N);
  }
  __syncthreads();
  if (t == 0) {
    double best = loss[0];
    for (int o = 1; o < 36; ++o) best = fmin(best, loss[o]);
    out[0] = (float)(-10.0 * log10(best));
  }
}

extern "C" void kernel_launch(void* const* d_in, const int* in_sizes, int n_in,
                              void* d_out, int out_size, void* d_ws, size_t ws_size,
                              hipStream_t stream) {
  const float* predict = (const float*)d_in[0];
  const float* target  = (const float*)d_in[1];
  const float* mask    = (const float*)d_in[2];
  float* out = (float*)d_out;

  float*  mpart = (float*)d_ws;                               // 40*756*4 = 120960 B
  double* epart = (double*)((char*)d_ws + NM * MSTRIDE * 4);  // 262*32*8 =  67072 B

  probav_fused_kernel<<<NPAD, 256, 0, stream>>>(predict, target, mask, mpart, epart);
  probav_final_kernel<<<1, 1024, 0, stream>>>(mpart, epart, out);
}